// Round 4
// baseline (7821.203 us; speedup 1.0000x reference)
//
#include <hip/hip_runtime.h>

#define N_NODES 100000
#define N_EDGES 800000
#define HDIM 100

typedef __attribute__((ext_vector_type(8))) short bf16x8;
typedef __attribute__((ext_vector_type(4))) float f32x4;

// ---------------- weight packing: W[batch][K][NC] fp32 -> transposed bf16 hi/lo [batch][NCpad][Kpad]
__global__ __launch_bounds__(256)
void pack_k(const float* __restrict__ W, ushort* __restrict__ hi, ushort* __restrict__ lo,
            int K, int NC, int Kpad, int NCpad, int total)
{
    int idx = blockIdx.x * 256 + threadIdx.x;
    if (idx >= total) return;
    int per = NCpad * Kpad;
    int b = idx / per, rem = idx - b * per;
    int col = rem / Kpad, k = rem - col * Kpad;
    float v = (col < NC && k < K) ? W[(long)b * K * NC + (long)k * NC + col] : 0.f;
    uint u = __float_as_uint(v);
    float r = v - __uint_as_float(u & 0xFFFF0000u);
    hi[idx] = (ushort)(u >> 16);
    lo[idx] = (ushort)(__float_as_uint(r) >> 16);
}

// ---------------- MFMA GEMM: C[M,NC] = epi(A[M,K] @ W[K,NC] + bias)
// NT: number of 16-col output tiles (NCpad = NT*16).
// MODE: 0 store, 1 relu+store, 2 C += 0.5*v
// GATHER: 0 plain A (lda stride); 1 row = cat(h[src],h[dst],e); 2 same + relu on h segs
// Split-precision: A,W decomposed hi+lo bf16; acc = aH*bH + aH*bL + aL*bH (fp32 accum).
template<int NT, int MODE, int GATHER>
__global__ __launch_bounds__(256, 3)
void gemm3_k(const float* __restrict__ A,
             const ushort* __restrict__ wtH, const ushort* __restrict__ wtL,
             const float* __restrict__ bias, float* __restrict__ C,
             int M, int K, int Kpad, int lda, int NC, int ldc,
             const int* __restrict__ src, const int* __restrict__ dst,
             const float* __restrict__ hbuf, const float* __restrict__ ebuf)
{
    __shared__ ushort AsH[64 * 64];   // [row][k] bf16, 128B row stride, XOR-swizzled
    __shared__ ushort AsL[64 * 64];
    __shared__ int sidx[64], didx[64];

    const int tid  = threadIdx.x;
    const int lane = tid & 63;
    const int w    = tid >> 6;              // wave id: rows w*16..w*16+15
    const long row0 = (long)blockIdx.x * 64;

    if (GATHER) {
        if (tid < 64) {
            long gr = row0 + tid;
            sidx[tid] = (gr < M) ? src[gr] : 0;
            didx[tid] = (gr < M) ? dst[gr] : 0;
        }
        __syncthreads();
    }

    f32x4 acc[NT];
#pragma unroll
    for (int t = 0; t < NT; ++t) acc[t] = (f32x4){0.f, 0.f, 0.f, 0.f};

    for (int k0 = 0; k0 < Kpad; k0 += 64) {
        // ---- stage A chunk 64 rows x 64 cols: fp32 -> bf16 hi/lo, swizzled ----
#pragma unroll
        for (int it = 0; it < 4; ++it) {
            int idx = tid + it * 256;         // 1024 float4-quads
            int r = idx >> 4, q = idx & 15;
            long grow = row0 + r;
            int gcol = k0 + q * 4;
            float4 v = make_float4(0.f, 0.f, 0.f, 0.f);
            if (GATHER) {
                if (grow < M && gcol < K) {   // segment boundaries (100,200) are 4-aligned
                    int seg = (gcol >= 200) ? 2 : (gcol >= 100 ? 1 : 0);
                    int off = gcol - seg * 100;
                    long rr = (seg == 0) ? (long)sidx[r] : (seg == 1) ? (long)didx[r] : grow;
                    const float* base = (seg == 2) ? ebuf : hbuf;
                    v = *(const float4*)&base[rr * HDIM + off];
                    if (GATHER == 2 && seg < 2) {
                        v.x = fmaxf(v.x, 0.f); v.y = fmaxf(v.y, 0.f);
                        v.z = fmaxf(v.z, 0.f); v.w = fmaxf(v.w, 0.f);
                    }
                }
            } else {
                if (grow < M) {
                    const float* ap = A + grow * (long)lda;
                    if (gcol + 3 < K) v = *(const float4*)(ap + gcol);
                    else {
                        if (gcol + 0 < K) v.x = ap[gcol + 0];
                        if (gcol + 1 < K) v.y = ap[gcol + 1];
                        if (gcol + 2 < K) v.z = ap[gcol + 2];
                        if (gcol + 3 < K) v.w = ap[gcol + 3];
                    }
                }
            }
            uint ux = __float_as_uint(v.x), uy = __float_as_uint(v.y);
            uint uz = __float_as_uint(v.z), uw = __float_as_uint(v.w);
            ushort4 hv = make_ushort4(ux >> 16, uy >> 16, uz >> 16, uw >> 16);
            float rx = v.x - __uint_as_float(ux & 0xFFFF0000u);
            float ry = v.y - __uint_as_float(uy & 0xFFFF0000u);
            float rz = v.z - __uint_as_float(uz & 0xFFFF0000u);
            float rw = v.w - __uint_as_float(uw & 0xFFFF0000u);
            ushort4 lv = make_ushort4(__float_as_uint(rx) >> 16, __float_as_uint(ry) >> 16,
                                      __float_as_uint(rz) >> 16, __float_as_uint(rw) >> 16);
            int boff = (r * 128 + q * 8) ^ ((r & 7) << 4);
            *(ushort4*)((char*)AsH + boff) = hv;
            *(ushort4*)((char*)AsL + boff) = lv;
        }
        __syncthreads();

        // ---- MFMA: 2 K-steps of 32 per chunk ----
        const int arow = w * 16 + (lane & 15);
        const int kgrp = lane >> 4;
#pragma unroll
        for (int ks = 0; ks < 2; ++ks) {
            int aoff = (arow * 128 + ks * 64 + kgrp * 16) ^ ((arow & 7) << 4);
            bf16x8 aH = *(const bf16x8*)((const char*)AsH + aoff);
            bf16x8 aL = *(const bf16x8*)((const char*)AsL + aoff);
            long kk = (long)k0 + ks * 32 + kgrp * 8;
#pragma unroll
            for (int t = 0; t < NT; ++t) {
                long coff = (long)(t * 16 + (lane & 15)) * Kpad + kk;
                bf16x8 bH = *(const bf16x8*)(wtH + coff);
                bf16x8 bL = *(const bf16x8*)(wtL + coff);
                acc[t] = __builtin_amdgcn_mfma_f32_16x16x32_bf16(aH, bH, acc[t], 0, 0, 0);
                acc[t] = __builtin_amdgcn_mfma_f32_16x16x32_bf16(aH, bL, acc[t], 0, 0, 0);
                acc[t] = __builtin_amdgcn_mfma_f32_16x16x32_bf16(aL, bH, acc[t], 0, 0, 0);
            }
        }
        __syncthreads();
    }

    // ---- epilogue: C/D layout col=lane&15, row=(lane>>4)*4+i ----
    const int cb = lane & 15;
    const int rg = lane >> 4;
#pragma unroll
    for (int t = 0; t < NT; ++t) {
        int col = t * 16 + cb;
        if (col >= NC) continue;
        float bv = bias[col];
#pragma unroll
        for (int i = 0; i < 4; ++i) {
            long grow = row0 + w * 16 + rg * 4 + i;
            if (grow >= M) continue;
            float v = acc[t][i] + bv;
            if (MODE == 1) v = fmaxf(v, 0.f);
            long o = grow * (long)ldc + col;
            if (MODE == 2) C[o] += 0.5f * v;
            else           C[o] = v;
        }
    }
}

// ---------------- message scatter: agg[dst] += relu(h[src] + tmp), float4 per thread
__global__ __launch_bounds__(256)
void msg_scatter4_k(const float* __restrict__ h, const float* __restrict__ tmp,
                    const int* __restrict__ src, const int* __restrict__ dst,
                    float* __restrict__ agg)
{
    unsigned idx = blockIdx.x * 256u + threadIdx.x;   // < E*25
    unsigned m = idx / 25u;
    unsigned q = (idx - m * 25u) * 4u;
    int s = src[m], d = dst[m];
    float4 t  = *(const float4*)&tmp[(long)m * HDIM + q];
    float4 hv = *(const float4*)&h[(long)s * HDIM + q];
    float* ap = &agg[(long)d * HDIM + q];
    atomicAdd(ap + 0, fmaxf(hv.x + t.x, 0.f));
    atomicAdd(ap + 1, fmaxf(hv.y + t.y, 0.f));
    atomicAdd(ap + 2, fmaxf(hv.z + t.z, 0.f));
    atomicAdd(ap + 3, fmaxf(hv.w + t.w, 0.f));
}

__global__ __launch_bounds__(128)
void bn_stats_k(const float* __restrict__ z, float* __restrict__ stats)
{
    int c = threadIdx.x;
    if (c >= HDIM) return;
    long rows_per = (N_NODES + gridDim.x - 1) / gridDim.x;
    long r0 = (long)blockIdx.x * rows_per;
    long r1 = r0 + rows_per; if (r1 > N_NODES) r1 = N_NODES;
    float s = 0.f, s2 = 0.f;
    for (long r = r0; r < r1; ++r) {
        float v = z[r * HDIM + c];
        s += v; s2 += v * v;
    }
    atomicAdd(&stats[c], s);
    atomicAdd(&stats[HDIM + c], s2);
}

__global__ __launch_bounds__(256)
void bn_apply_k(const float* __restrict__ z, const float* __restrict__ stats,
                const float* __restrict__ gamma, const float* __restrict__ beta,
                float* __restrict__ h)
{
    unsigned idx = blockIdx.x * 256u + threadIdx.x;
    if (idx >= (unsigned)(N_NODES * HDIM)) return;
    unsigned c = idx % HDIM;
    const float invN = 1.f / N_NODES;
    float mu  = stats[c] * invN;
    float var = stats[HDIM + c] * invN - mu * mu;
    float v = (z[idx] - mu) * rsqrtf(var + 1e-5f) * gamma[c] + beta[c];
    h[idx] = (h[idx] + fmaxf(v, 0.f)) * 0.5f;
}

// out[E,2] = f2[E,25] @ mw3[25,2] + mb3
__global__ __launch_bounds__(256)
void final_out_k(const float* __restrict__ f2, const float* __restrict__ W,
                 const float* __restrict__ b, float* __restrict__ out)
{
    unsigned m = blockIdx.x * 256u + threadIdx.x;
    if (m >= N_EDGES) return;
    float a0 = b[0], a1 = b[1];
    const float* row = &f2[(long)m * 25];
#pragma unroll
    for (int k = 0; k < 25; ++k) {
        float v = row[k];
        a0 += v * W[k * 2 + 0];
        a1 += v * W[k * 2 + 1];
    }
    out[(long)m * 2 + 0] = a0;
    out[(long)m * 2 + 1] = a1;
}

static inline int gb64(long m) { return (int)((m + 63) / 64); }

extern "C" void kernel_launch(void* const* d_in, const int* in_sizes, int n_in,
                              void* d_out, int out_size, void* d_ws, size_t ws_size,
                              hipStream_t stream)
{
    const float* x         = (const float*)d_in[0];
    const int*   ei        = (const int*)  d_in[1];
    const float* edge_attr = (const float*)d_in[2];
    const float* node_w    = (const float*)d_in[3];
    const float* node_b    = (const float*)d_in[4];
    const float* edge_w    = (const float*)d_in[5];
    const float* edge_b    = (const float*)d_in[6];
    const float* lin_w     = (const float*)d_in[7];
    const float* lin_b     = (const float*)d_in[8];
    const float* w1        = (const float*)d_in[9];
    const float* b1        = (const float*)d_in[10];
    const float* w2        = (const float*)d_in[11];
    const float* b2        = (const float*)d_in[12];
    const float* gamma     = (const float*)d_in[13];
    const float* beta      = (const float*)d_in[14];
    const float* ew1       = (const float*)d_in[15];
    const float* eb1       = (const float*)d_in[16];
    const float* ew2       = (const float*)d_in[17];
    const float* eb2       = (const float*)d_in[18];
    const float* mw1       = (const float*)d_in[19];
    const float* mb1       = (const float*)d_in[20];
    const float* mw2       = (const float*)d_in[21];
    const float* mb2       = (const float*)d_in[22];
    const float* mw3       = (const float*)d_in[23];
    const float* mb3       = (const float*)d_in[24];
    float* out = (float*)d_out;

    // ---- workspace: packed weights (1 MB) then fp32 activations ----
    ushort* pw = (ushort*)d_ws;
    size_t off = 0;
    ushort *nwH, *nwL, *ewH, *ewL, *liH, *liL, *w1H, *w1L, *w2H, *w2L,
           *e1H, *e1L, *e2H, *e2L, *m1H, *m1L, *m2H, *m2L;
    auto nextw = [&](size_t s, ushort*& H, ushort*& L) { H = pw + off; L = pw + off + s; off += 2 * s; };
    nextw(112 * 128,       nwH, nwL);   // node_w   K=128 NC=100
    nextw(112 * 64,        ewH, ewL);   // edge_w   K=64
    nextw(2 * 112 * 128,   liH, liL);   // lin_w    K=100 x2
    nextw(2 * 112 * 128,   w1H, w1L);
    nextw(2 * 112 * 128,   w2H, w2L);
    nextw(2 * 112 * 320,   e1H, e1L);   // ew1      K=300 x2
    nextw(2 * 112 * 128,   e2H, e2L);
    nextw(64 * 320,        m1H, m1L);   // mw1      K=300 NC=50
    nextw(32 * 64,         m2H, m2L);   // mw2      K=50  NC=25

    float* fbase = (float*)((char*)d_ws + 1048576);
    float* e     = fbase;                                  // E*100
    float* tmp   = e   + (size_t)N_EDGES * HDIM;           // E*100 (also z, f1, f2)
    float* h     = tmp + (size_t)N_EDGES * HDIM;           // N*100
    float* agg   = h   + (size_t)N_NODES * HDIM;           // N*100
    float* stats = agg + (size_t)N_NODES * HDIM;           // 256
    float* z  = tmp;
    float* f1 = tmp;                                       // E*52 (stride 52 for 16B align)
    float* f2 = tmp + (size_t)N_EDGES * 52;                // E*25

    const int* srcp = ei;
    const int* dstp = ei + N_EDGES;
    dim3 blk(256);

    // ---- pack all weights (bf16 hi/lo, transposed) ----
    auto packl = [&](const float* W, ushort* H, ushort* L, int K, int NC, int Kp, int NCp, int batch) {
        int total = batch * NCp * Kp;
        pack_k<<<(total + 255) / 256, blk, 0, stream>>>(W, H, L, K, NC, Kp, NCp, total);
    };
    packl(node_w, nwH, nwL, 128, 100, 128, 112, 1);
    packl(edge_w, ewH, ewL,  64, 100,  64, 112, 1);
    packl(lin_w,  liH, liL, 100, 100, 128, 112, 2);
    packl(w1,     w1H, w1L, 100, 100, 128, 112, 2);
    packl(w2,     w2H, w2L, 100, 100, 128, 112, 2);
    packl(ew1,    e1H, e1L, 300, 100, 320, 112, 2);
    packl(ew2,    e2H, e2L, 100, 100, 128, 112, 2);
    packl(mw1,    m1H, m1L, 300,  50, 320,  64, 1);
    packl(mw2,    m2H, m2L,  50,  25,  64,  32, 1);

    // 1. h = x @ node_w + node_b
    gemm3_k<7,0,0><<<gb64(N_NODES), blk, 0, stream>>>(
        x, nwH, nwL, node_b, h, N_NODES, 128, 128, 128, 100, 100,
        nullptr, nullptr, nullptr, nullptr);
    // 2. e = edge_attr @ edge_w + edge_b
    gemm3_k<7,0,0><<<gb64(N_EDGES), blk, 0, stream>>>(
        edge_attr, ewH, ewL, edge_b, e, N_EDGES, 64, 64, 64, 100, 100,
        nullptr, nullptr, nullptr, nullptr);

    for (int i = 0; i < 2; ++i) {
        // 3. tmp = e @ lin_w[i] + lin_b[i]
        gemm3_k<7,0,0><<<gb64(N_EDGES), blk, 0, stream>>>(
            e, liH + (size_t)i * 14336, liL + (size_t)i * 14336, lin_b + i * HDIM, tmp,
            N_EDGES, 100, 128, 100, 100, 100, nullptr, nullptr, nullptr, nullptr);
        // 4. agg = h
        hipMemcpyAsync(agg, h, (size_t)N_NODES * HDIM * sizeof(float),
                       hipMemcpyDeviceToDevice, stream);
        // 5. agg[dst] += relu(h[src] + tmp)
        msg_scatter4_k<<<(N_EDGES * 25) / 256, blk, 0, stream>>>(h, tmp, srcp, dstp, agg);
        // 6. z = relu(agg @ w1[i] + b1[i])
        gemm3_k<7,1,0><<<gb64(N_NODES), blk, 0, stream>>>(
            agg, w1H + (size_t)i * 14336, w1L + (size_t)i * 14336, b1 + i * HDIM, z,
            N_NODES, 100, 128, 100, 100, 100, nullptr, nullptr, nullptr, nullptr);
        // 7. agg = z @ w2[i] + b2[i]
        gemm3_k<7,0,0><<<gb64(N_NODES), blk, 0, stream>>>(
            z, w2H + (size_t)i * 14336, w2L + (size_t)i * 14336, b2 + i * HDIM, agg,
            N_NODES, 100, 128, 100, 100, 100, nullptr, nullptr, nullptr, nullptr);
        // 8. BN stats
        hipMemsetAsync(stats, 0, 2 * HDIM * sizeof(float), stream);
        bn_stats_k<<<1024, dim3(128), 0, stream>>>(agg, stats);
        // 9. h = (h + relu(BN(agg))) / 2
        bn_apply_k<<<(N_NODES * HDIM + 255) / 256, blk, 0, stream>>>(
            agg, stats, gamma + i * HDIM, beta + i * HDIM, h);
        // 10. tmp = relu(cat(h[src],h[dst],e) @ ew1[i] + eb1[i])   K=300
        gemm3_k<7,1,1><<<gb64(N_EDGES), blk, 0, stream>>>(
            nullptr, e1H + (size_t)i * 35840, e1L + (size_t)i * 35840, eb1 + i * HDIM, tmp,
            N_EDGES, 300, 320, 0, 100, 100, srcp, dstp, h, e);
        // 11. e = e + 0.5*(tmp @ ew2[i] + eb2[i])
        gemm3_k<7,2,0><<<gb64(N_EDGES), blk, 0, stream>>>(
            tmp, e2H + (size_t)i * 14336, e2L + (size_t)i * 14336, eb2 + i * HDIM, e,
            N_EDGES, 100, 128, 100, 100, 100, nullptr, nullptr, nullptr, nullptr);
    }

    // 12. f1 = relu(cat(relu(h[src]),relu(h[dst]),e) @ mw1 + mb1)   K=300, ldc=52
    gemm3_k<4,1,2><<<gb64(N_EDGES), blk, 0, stream>>>(
        nullptr, m1H, m1L, mb1, f1, N_EDGES, 300, 320, 0, 50, 52, srcp, dstp, h, e);
    // 13. f2 = relu(f1 @ mw2 + mb2)   K=50 (lda=52)
    gemm3_k<2,1,0><<<gb64(N_EDGES), blk, 0, stream>>>(
        f1, m2H, m2L, mb2, f2, N_EDGES, 50, 64, 52, 25, 25,
        nullptr, nullptr, nullptr, nullptr);
    // 14. out = f2 @ mw3 + mb3
    final_out_k<<<N_EDGES / 256, blk, 0, stream>>>(f2, mw3, mb3, out);
}

// Round 5
// 4598.180 us; speedup vs baseline: 1.7009x; 1.7009x over previous
//
#include <hip/hip_runtime.h>

#define N_NODES 100000
#define N_EDGES 800000
#define HDIM 100

typedef __attribute__((ext_vector_type(8))) short bf16x8;
typedef __attribute__((ext_vector_type(4))) float f32x4;

// ---------------- weight packing: W[batch][K][NC] fp32 -> transposed bf16 hi/lo [batch][NCpad][Kpad]
__global__ __launch_bounds__(256)
void pack_k(const float* __restrict__ W, ushort* __restrict__ hi, ushort* __restrict__ lo,
            int K, int NC, int Kpad, int NCpad, int total)
{
    int idx = blockIdx.x * 256 + threadIdx.x;
    if (idx >= total) return;
    int per = NCpad * Kpad;
    int b = idx / per, rem = idx - b * per;
    int col = rem / Kpad, k = rem - col * Kpad;
    float v = (col < NC && k < K) ? W[(long)b * K * NC + (long)k * NC + col] : 0.f;
    uint u = __float_as_uint(v);
    float r = v - __uint_as_float(u & 0xFFFF0000u);
    hi[idx] = (ushort)(u >> 16);
    lo[idx] = (ushort)(__float_as_uint(r) >> 16);
}

// ---------------- MFMA GEMM, persistent-register B.
// TILES: 16-col output tiles (NCpad=TILES*16); TPW: tiles per wave (WAVES=TILES/TPW must be 4... block=WAVES*64=256)
// KS: K-steps of 32 (Kpad=KS*32). MODE: 0 store, 1 relu, 2 C+=0.5v. GATHER: 0 plain, 1 cat(h[s],h[d],e), 2 +relu on h.
// Split precision: acc = aH*bH + aH*bL + aL*bH, fp32 accum.
template<int TILES, int TPW, int KS, int MODE, int GATHER, int MINW>
__global__ __launch_bounds__(256, MINW)
void gemm5_k(const float* __restrict__ A,
             const ushort* __restrict__ wtH, const ushort* __restrict__ wtL,
             const float* __restrict__ bias, float* __restrict__ C,
             int M, int K, int lda, int NC, int ldc,
             const int* __restrict__ src, const int* __restrict__ dst,
             const float* __restrict__ hbuf, const float* __restrict__ ebuf)
{
    constexpr int WAVES = TILES / TPW;
    constexpr int KPAD  = KS * 32;
    static_assert(WAVES * 64 == 256, "block must be 256 threads");
    __shared__ ushort AsH[64 * 64];   // 64 rows x 64 k, 128B row, XOR-swizzled
    __shared__ ushort AsL[64 * 64];
    __shared__ int sidx[64], didx[64];

    const int tid  = threadIdx.x;
    const int lane = tid & 63;
    const int w    = tid >> 6;
    const long row0 = (long)blockIdx.x * 64;

    // ---- load this wave's B fragments into registers (once per block) ----
    bf16x8 bH[TPW][KS], bL[TPW][KS];
#pragma unroll
    for (int tp = 0; tp < TPW; ++tp) {
        int col = (w * TPW + tp) * 16 + (lane & 15);
#pragma unroll
        for (int kk = 0; kk < KS; ++kk) {
            long o = (long)col * KPAD + kk * 32 + (lane >> 4) * 8;
            bH[tp][kk] = *(const bf16x8*)(wtH + o);
            bL[tp][kk] = *(const bf16x8*)(wtL + o);
        }
    }

    if (GATHER) {
        if (tid < 64) {
            long gr = row0 + tid;
            sidx[tid] = (gr < M) ? src[gr] : 0;
            didx[tid] = (gr < M) ? dst[gr] : 0;
        }
        __syncthreads();
    }

    f32x4 acc[TPW][4];
#pragma unroll
    for (int tp = 0; tp < TPW; ++tp)
#pragma unroll
        for (int rg = 0; rg < 4; ++rg) acc[tp][rg] = (f32x4){0.f, 0.f, 0.f, 0.f};

#pragma unroll
    for (int c = 0; c < KS / 2; ++c) {
        // ---- stage A chunk 64 rows x 64 k: fp32 -> bf16 hi/lo, swizzled ----
#pragma unroll
        for (int it = 0; it < 4; ++it) {
            int idx = tid + it * 256;
            int r = idx >> 4, q = idx & 15;
            long grow = row0 + r;
            int gcol = c * 64 + q * 4;
            float4 v = make_float4(0.f, 0.f, 0.f, 0.f);
            if (GATHER) {
                if (grow < M && gcol < K) {       // segment bounds (100,200) are 4-aligned
                    int seg = (gcol >= 200) ? 2 : (gcol >= 100 ? 1 : 0);
                    int off = gcol - seg * 100;
                    long rr = (seg == 0) ? (long)sidx[r] : (seg == 1) ? (long)didx[r] : grow;
                    const float* base = (seg == 2) ? ebuf : hbuf;
                    v = *(const float4*)&base[rr * HDIM + off];
                    if (GATHER == 2 && seg < 2) {
                        v.x = fmaxf(v.x, 0.f); v.y = fmaxf(v.y, 0.f);
                        v.z = fmaxf(v.z, 0.f); v.w = fmaxf(v.w, 0.f);
                    }
                }
            } else {
                if (grow < M) {
                    const float* ap = A + grow * (long)lda;
                    if (gcol + 3 < K) v = *(const float4*)(ap + gcol);
                    else {
                        if (gcol + 0 < K) v.x = ap[gcol + 0];
                        if (gcol + 1 < K) v.y = ap[gcol + 1];
                        if (gcol + 2 < K) v.z = ap[gcol + 2];
                        if (gcol + 3 < K) v.w = ap[gcol + 3];
                    }
                }
            }
            uint ux = __float_as_uint(v.x), uy = __float_as_uint(v.y);
            uint uz = __float_as_uint(v.z), uw = __float_as_uint(v.w);
            ushort4 hv = make_ushort4(ux >> 16, uy >> 16, uz >> 16, uw >> 16);
            float rx = v.x - __uint_as_float(ux & 0xFFFF0000u);
            float ry = v.y - __uint_as_float(uy & 0xFFFF0000u);
            float rz = v.z - __uint_as_float(uz & 0xFFFF0000u);
            float rw = v.w - __uint_as_float(uw & 0xFFFF0000u);
            ushort4 lv = make_ushort4(__float_as_uint(rx) >> 16, __float_as_uint(ry) >> 16,
                                      __float_as_uint(rz) >> 16, __float_as_uint(rw) >> 16);
            int boff = (r * 128 + q * 8) ^ ((r & 7) << 4);
            *(ushort4*)((char*)AsH + boff) = hv;
            *(ushort4*)((char*)AsL + boff) = lv;
        }
        __syncthreads();

        // ---- MFMA: 2 K-steps of 32; B from registers ----
#pragma unroll
        for (int ks = 0; ks < 2; ++ks) {
            constexpr int dummy = 0; (void)dummy;
#pragma unroll
            for (int rg = 0; rg < 4; ++rg) {
                int arow = rg * 16 + (lane & 15);
                int aoff = (arow * 128 + ks * 64 + (lane >> 4) * 16) ^ ((arow & 7) << 4);
                bf16x8 aH = *(const bf16x8*)((const char*)AsH + aoff);
                bf16x8 aL = *(const bf16x8*)((const char*)AsL + aoff);
#pragma unroll
                for (int tp = 0; tp < TPW; ++tp) {
                    acc[tp][rg] = __builtin_amdgcn_mfma_f32_16x16x32_bf16(aH, bH[tp][c * 2 + ks], acc[tp][rg], 0, 0, 0);
                    acc[tp][rg] = __builtin_amdgcn_mfma_f32_16x16x32_bf16(aH, bL[tp][c * 2 + ks], acc[tp][rg], 0, 0, 0);
                    acc[tp][rg] = __builtin_amdgcn_mfma_f32_16x16x32_bf16(aL, bH[tp][c * 2 + ks], acc[tp][rg], 0, 0, 0);
                }
            }
        }
        __syncthreads();
    }

    // ---- epilogue: C/D layout col=lane&15, row=(lane>>4)*4+i ----
#pragma unroll
    for (int tp = 0; tp < TPW; ++tp) {
        int col = (w * TPW + tp) * 16 + (lane & 15);
        if (col >= NC) continue;
        float bv = bias[col];
#pragma unroll
        for (int rg = 0; rg < 4; ++rg) {
#pragma unroll
            for (int i = 0; i < 4; ++i) {
                long grow = row0 + rg * 16 + (lane >> 4) * 4 + i;
                if (grow >= M) continue;
                float v = acc[tp][rg][i] + bv;
                if (MODE == 1) v = fmaxf(v, 0.f);
                long o = grow * (long)ldc + col;
                if (MODE == 2) C[o] += 0.5f * v;
                else           C[o] = v;
            }
        }
    }
}

// ---------------- CSR build (graph is static: build once per launch) ----------------
__global__ __launch_bounds__(256)
void hist_k(const int* __restrict__ dst, int* __restrict__ cnt)
{
    int e = blockIdx.x * 256 + threadIdx.x;
    if (e < N_EDGES) atomicAdd(&cnt[dst[e]], 1);
}

__global__ __launch_bounds__(1024)
void scan_k(const int* __restrict__ cnt, int* __restrict__ off)
{
    __shared__ int part[1024];
    const int t = threadIdx.x;
    const int per = (N_NODES + 1023) / 1024;
    const int base = t * per;
    int s = 0;
    for (int i = 0; i < per; ++i) {
        int n = base + i;
        if (n < N_NODES) s += cnt[n];
    }
    part[t] = s;
    __syncthreads();
    for (int d = 1; d < 1024; d <<= 1) {
        int v = (t >= d) ? part[t - d] : 0;
        __syncthreads();
        part[t] += v;
        __syncthreads();
    }
    int run = (t == 0) ? 0 : part[t - 1];
    for (int i = 0; i < per; ++i) {
        int n = base + i;
        if (n < N_NODES) { off[n] = run; run += cnt[n]; }
    }
    if (t == 1023) off[N_NODES] = run;
}

__global__ __launch_bounds__(256)
void fill_k(const int* __restrict__ dst, const int* __restrict__ off,
            int* __restrict__ pos, int* __restrict__ eidx)
{
    int e = blockIdx.x * 256 + threadIdx.x;
    if (e >= N_EDGES) return;
    int d = dst[e];
    int p = atomicAdd(&pos[d], 1);
    eidx[off[d] + p] = e;
}

// ---------------- aggregation: agg[n] = h[n] + sum_{e: dst=n} relu(h[src[e]] + tmp[e])
__global__ __launch_bounds__(256)
void agg_k(const float* __restrict__ h, const float* __restrict__ tmp,
           const int* __restrict__ src, const int* __restrict__ off,
           const int* __restrict__ eidx, float* __restrict__ agg)
{
    unsigned idx = blockIdx.x * 256u + threadIdx.x;
    if (idx >= (unsigned)(N_NODES * 25)) return;
    unsigned n = idx / 25u;
    unsigned q = (idx - n * 25u) * 4u;
    float4 a = *(const float4*)&h[(long)n * HDIM + q];
    int j0 = off[n], j1 = off[n + 1];
    for (int j = j0; j < j1; ++j) {
        int e = eidx[j];
        int s = src[e];
        float4 t  = *(const float4*)&tmp[(long)e * HDIM + q];
        float4 hv = *(const float4*)&h[(long)s * HDIM + q];
        a.x += fmaxf(hv.x + t.x, 0.f);
        a.y += fmaxf(hv.y + t.y, 0.f);
        a.z += fmaxf(hv.z + t.z, 0.f);
        a.w += fmaxf(hv.w + t.w, 0.f);
    }
    *(float4*)&agg[(long)n * HDIM + q] = a;
}

__global__ __launch_bounds__(128)
void bn_stats_k(const float* __restrict__ z, float* __restrict__ stats)
{
    int c = threadIdx.x;
    if (c >= HDIM) return;
    long rows_per = (N_NODES + gridDim.x - 1) / gridDim.x;
    long r0 = (long)blockIdx.x * rows_per;
    long r1 = r0 + rows_per; if (r1 > N_NODES) r1 = N_NODES;
    float s = 0.f, s2 = 0.f;
    for (long r = r0; r < r1; ++r) {
        float v = z[r * HDIM + c];
        s += v; s2 += v * v;
    }
    atomicAdd(&stats[c], s);
    atomicAdd(&stats[HDIM + c], s2);
}

__global__ __launch_bounds__(256)
void bn_apply_k(const float* __restrict__ z, const float* __restrict__ stats,
                const float* __restrict__ gamma, const float* __restrict__ beta,
                float* __restrict__ h)
{
    unsigned idx = blockIdx.x * 256u + threadIdx.x;
    if (idx >= (unsigned)(N_NODES * HDIM)) return;
    unsigned c = idx % HDIM;
    const float invN = 1.f / N_NODES;
    float mu  = stats[c] * invN;
    float var = stats[HDIM + c] * invN - mu * mu;
    float v = (z[idx] - mu) * rsqrtf(var + 1e-5f) * gamma[c] + beta[c];
    h[idx] = (h[idx] + fmaxf(v, 0.f)) * 0.5f;
}

// out[E,2] = f2[E,25] @ mw3[25,2] + mb3
__global__ __launch_bounds__(256)
void final_out_k(const float* __restrict__ f2, const float* __restrict__ W,
                 const float* __restrict__ b, float* __restrict__ out)
{
    unsigned m = blockIdx.x * 256u + threadIdx.x;
    if (m >= N_EDGES) return;
    float a0 = b[0], a1 = b[1];
    const float* row = &f2[(long)m * 25];
#pragma unroll
    for (int k = 0; k < 25; ++k) {
        float v = row[k];
        a0 += v * W[k * 2 + 0];
        a1 += v * W[k * 2 + 1];
    }
    out[(long)m * 2 + 0] = a0;
    out[(long)m * 2 + 1] = a1;
}

static inline int gb64(long m) { return (int)((m + 63) / 64); }

extern "C" void kernel_launch(void* const* d_in, const int* in_sizes, int n_in,
                              void* d_out, int out_size, void* d_ws, size_t ws_size,
                              hipStream_t stream)
{
    const float* x         = (const float*)d_in[0];
    const int*   ei        = (const int*)  d_in[1];
    const float* edge_attr = (const float*)d_in[2];
    const float* node_w    = (const float*)d_in[3];
    const float* node_b    = (const float*)d_in[4];
    const float* edge_w    = (const float*)d_in[5];
    const float* edge_b    = (const float*)d_in[6];
    const float* lin_w     = (const float*)d_in[7];
    const float* lin_b     = (const float*)d_in[8];
    const float* w1        = (const float*)d_in[9];
    const float* b1        = (const float*)d_in[10];
    const float* w2        = (const float*)d_in[11];
    const float* b2        = (const float*)d_in[12];
    const float* gamma     = (const float*)d_in[13];
    const float* beta      = (const float*)d_in[14];
    const float* ew1       = (const float*)d_in[15];
    const float* eb1       = (const float*)d_in[16];
    const float* ew2       = (const float*)d_in[17];
    const float* eb2       = (const float*)d_in[18];
    const float* mw1       = (const float*)d_in[19];
    const float* mb1       = (const float*)d_in[20];
    const float* mw2       = (const float*)d_in[21];
    const float* mb2       = (const float*)d_in[22];
    const float* mw3       = (const float*)d_in[23];
    const float* mb3       = (const float*)d_in[24];
    float* out = (float*)d_out;

    // ---- workspace layout: [0,1MB) packed weights | [1MB,8MB) CSR ints | floats ----
    ushort* pw = (ushort*)d_ws;
    size_t off_w = 0;
    ushort *nwH, *nwL, *ewH, *ewL, *liH, *liL, *w1H, *w1L, *w2H, *w2L,
           *e1H, *e1L, *e2H, *e2L, *m1H, *m1L, *m2H, *m2L;
    auto nextw = [&](size_t s, ushort*& H, ushort*& L) { H = pw + off_w; L = pw + off_w + s; off_w += 2 * s; };
    nextw(128 * 128,     nwH, nwL);   // node_w  K=128  NCpad=128
    nextw(128 * 64,      ewH, ewL);   // edge_w  K=64
    nextw(2 * 128 * 128, liH, liL);   // lin_w x2
    nextw(2 * 128 * 128, w1H, w1L);
    nextw(2 * 128 * 128, w2H, w2L);
    nextw(2 * 128 * 320, e1H, e1L);   // ew1 x2  K=300
    nextw(2 * 128 * 128, e2H, e2L);
    nextw(64 * 320,      m1H, m1L);   // mw1     K=300 NCpad=64
    nextw(64 * 64,       m2H, m2L);   // mw2     K=50  NCpad=64

    int* intb = (int*)((char*)d_ws + (1 << 20));
    int* cnt  = intb;                  // N
    int* coff = cnt + N_NODES;         // N+1
    int* pos  = coff + N_NODES + 1;    // N
    int* eidx = pos + N_NODES;         // E

    float* fbase = (float*)((char*)d_ws + (8u << 20));
    float* e     = fbase;                                  // E*100
    float* tmp   = e   + (size_t)N_EDGES * HDIM;           // E*100 (also z, f1, f2)
    float* h     = tmp + (size_t)N_EDGES * HDIM;           // N*100
    float* agg   = h   + (size_t)N_NODES * HDIM;           // N*100
    float* stats = agg + (size_t)N_NODES * HDIM;           // 256
    float* z  = tmp;
    float* f1 = tmp;                                       // E*52
    float* f2 = tmp + (size_t)N_EDGES * 52;                // E*25

    const int* srcp = ei;
    const int* dstp = ei + N_EDGES;
    dim3 blk(256);

    // ---- pack weights ----
    auto packl = [&](const float* W, ushort* H, ushort* L, int K, int NC, int Kp, int NCp, int batch) {
        int total = batch * NCp * Kp;
        pack_k<<<(total + 255) / 256, blk, 0, stream>>>(W, H, L, K, NC, Kp, NCp, total);
    };
    packl(node_w, nwH, nwL, 128, 100, 128, 128, 1);
    packl(edge_w, ewH, ewL,  64, 100,  64, 128, 1);
    packl(lin_w,  liH, liL, 100, 100, 128, 128, 2);
    packl(w1,     w1H, w1L, 100, 100, 128, 128, 2);
    packl(w2,     w2H, w2L, 100, 100, 128, 128, 2);
    packl(ew1,    e1H, e1L, 300, 100, 320, 128, 2);
    packl(ew2,    e2H, e2L, 100, 100, 128, 128, 2);
    packl(mw1,    m1H, m1L, 300,  50, 320,  64, 1);
    packl(mw2,    m2H, m2L,  50,  25,  64,  64, 1);

    // ---- build CSR once (graph static across layers) ----
    hipMemsetAsync(cnt, 0, N_NODES * sizeof(int), stream);
    hist_k<<<(N_EDGES + 255) / 256, blk, 0, stream>>>(dstp, cnt);
    scan_k<<<1, dim3(1024), 0, stream>>>(cnt, coff);
    hipMemsetAsync(pos, 0, N_NODES * sizeof(int), stream);
    fill_k<<<(N_EDGES + 255) / 256, blk, 0, stream>>>(dstp, coff, pos, eidx);

    // 1. h = x @ node_w + node_b            K=128
    gemm5_k<8,2,4,0,0,3><<<gb64(N_NODES), blk, 0, stream>>>(
        x, nwH, nwL, node_b, h, N_NODES, 128, 128, 100, 100,
        nullptr, nullptr, nullptr, nullptr);
    // 2. e = edge_attr @ edge_w + edge_b    K=64
    gemm5_k<8,2,2,0,0,3><<<gb64(N_EDGES), blk, 0, stream>>>(
        edge_attr, ewH, ewL, edge_b, e, N_EDGES, 64, 64, 100, 100,
        nullptr, nullptr, nullptr, nullptr);

    for (int i = 0; i < 2; ++i) {
        // 3. tmp = e @ lin_w[i] + lin_b[i]
        gemm5_k<8,2,4,0,0,3><<<gb64(N_EDGES), blk, 0, stream>>>(
            e, liH + (size_t)i * 16384, liL + (size_t)i * 16384, lin_b + i * HDIM, tmp,
            N_EDGES, 100, 100, 100, 100, nullptr, nullptr, nullptr, nullptr);
        // 4+5. agg = h + sum relu(h[src] + tmp)   (CSR gather)
        agg_k<<<(N_NODES * 25 + 255) / 256, blk, 0, stream>>>(h, tmp, srcp, coff, eidx, agg);
        // 6. z = relu(agg @ w1[i] + b1[i])
        gemm5_k<8,2,4,1,0,3><<<gb64(N_NODES), blk, 0, stream>>>(
            agg, w1H + (size_t)i * 16384, w1L + (size_t)i * 16384, b1 + i * HDIM, z,
            N_NODES, 100, 100, 100, 100, nullptr, nullptr, nullptr, nullptr);
        // 7. agg = z @ w2[i] + b2[i]
        gemm5_k<8,2,4,0,0,3><<<gb64(N_NODES), blk, 0, stream>>>(
            z, w2H + (size_t)i * 16384, w2L + (size_t)i * 16384, b2 + i * HDIM, agg,
            N_NODES, 100, 100, 100, 100, nullptr, nullptr, nullptr, nullptr);
        // 8. BN stats
        hipMemsetAsync(stats, 0, 2 * HDIM * sizeof(float), stream);
        bn_stats_k<<<1024, dim3(128), 0, stream>>>(agg, stats);
        // 9. h = (h + relu(BN(agg))) / 2
        bn_apply_k<<<(N_NODES * HDIM + 255) / 256, blk, 0, stream>>>(
            agg, stats, gamma + i * HDIM, beta + i * HDIM, h);
        // 10. tmp = relu(cat(h[src],h[dst],e) @ ew1[i] + eb1[i])   K=300
        gemm5_k<8,2,10,1,1,2><<<gb64(N_EDGES), blk, 0, stream>>>(
            nullptr, e1H + (size_t)i * 40960, e1L + (size_t)i * 40960, eb1 + i * HDIM, tmp,
            N_EDGES, 300, 0, 100, 100, srcp, dstp, h, e);
        // 11. e = e + 0.5*(tmp @ ew2[i] + eb2[i])
        gemm5_k<8,2,4,2,0,3><<<gb64(N_EDGES), blk, 0, stream>>>(
            tmp, e2H + (size_t)i * 16384, e2L + (size_t)i * 16384, eb2 + i * HDIM, e,
            N_EDGES, 100, 100, 100, 100, nullptr, nullptr, nullptr, nullptr);
    }

    // 12. f1 = relu(cat(relu(h[src]),relu(h[dst]),e) @ mw1 + mb1)   K=300, ldc=52
    gemm5_k<4,1,10,1,2,3><<<gb64(N_EDGES), blk, 0, stream>>>(
        nullptr, m1H, m1L, mb1, f1, N_EDGES, 300, 0, 50, 52, srcp, dstp, h, e);
    // 13. f2 = relu(f1 @ mw2 + mb2)   K=50 (lda=52)
    gemm5_k<4,1,2,1,0,3><<<gb64(N_EDGES), blk, 0, stream>>>(
        f1, m2H, m2L, mb2, f2, N_EDGES, 50, 52, 25, 25,
        nullptr, nullptr, nullptr, nullptr);
    // 14. out = f2 @ mw3 + mb3
    final_out_k<<<N_EDGES / 256, blk, 0, stream>>>(f2, mw3, mb3, out);
}